// Round 4
// baseline (691.875 us; speedup 1.0000x reference)
//
#include <hip/hip_runtime.h>
#include <stdint.h>

#define DIM 1024
#define HEADS 16
#define HD 64
#define NC 8
#define BB 4
#define NN 1024
#define ROWS (BB*NN)            // 4096
#define TOK (BB*HEADS*NN)       // 65536
#define OUT_OFF_Z (ROWS*DIM)    // 4194304
#define CP_OFF    (ROWS*DIM+3)  // 4194307

typedef __bf16 bf16_t;
typedef __attribute__((ext_vector_type(8))) __bf16 bf16x8;
typedef __attribute__((ext_vector_type(4))) __bf16 bf16x4;
typedef __attribute__((ext_vector_type(4))) float f32x4;

__device__ __forceinline__ void gload16(const void* g, void* l){
#if __has_builtin(__builtin_amdgcn_global_load_lds)
  __builtin_amdgcn_global_load_lds(
      (__attribute__((address_space(1))) void*)(g),
      (__attribute__((address_space(3))) void*)(l), 16, 0, 0);
#else
  *(uint4*)l = *(const uint4*)g;
#endif
}

// ======== fused prep: x->bf16, Wqkv^T, Wproj^T, sigmoid(affB), zero scalars ========
__global__ __launch_bounds__(256) void prep_kernel(
    const float* __restrict__ x, const float* __restrict__ Wqkv,
    const float* __restrict__ Wproj, const float* __restrict__ affB,
    bf16_t* __restrict__ xb, bf16_t* __restrict__ WqkvT, bf16_t* __restrict__ WprojT,
    float* __restrict__ sigB, float* __restrict__ out_scalars){
  const int bid = blockIdx.x, tid = threadIdx.x;
  if(bid < 4096){                       // cvt x -> xb (4M elems, 1024/block)
    int i = (bid*256 + tid)*4;
    float4 v = *(const float4*)&x[i];
    bf16x4 o = {(bf16_t)v.x, (bf16_t)v.y, (bf16_t)v.z, (bf16_t)v.w};
    *(bf16x4*)&xb[i] = o;
    return;
  }
  if(bid < 8192){                       // transposes
    __shared__ float tile[32][33];
    const float* in; bf16_t* out; int K, N, bx, by;
    if(bid < 7168){ int t = bid-4096; in = Wqkv;  out = WqkvT;  K = 1024; N = 3072; bx = t%96; by = t/96; }
    else          { int t = bid-7168; in = Wproj; out = WprojT; K = 1024; N = 1024; bx = t%32; by = t/32; }
    int k0 = by*32, n0 = bx*32;
    int tx = tid & 31, ty = tid >> 5;   // 32 x 8
    #pragma unroll
    for(int r=ty; r<32; r+=8) tile[r][tx] = in[(size_t)(k0+r)*N + n0+tx];
    __syncthreads();
    #pragma unroll
    for(int r=ty; r<32; r+=8) out[(size_t)(n0+r)*K + k0+tx] = (bf16_t)tile[tx][r];
    return;
  }
  // small tail: sigB (1024) + zero 3 out scalars
  #pragma unroll
  for(int r=0;r<4;r++){
    int i = r*256 + tid;
    sigB[i] = 1.f/(1.f + __expf(-affB[i]));
  }
  if(tid < 3) out_scalars[tid] = 0.f;
}

// ======== merged QKV GEMM: 768 blocks; [0,512)=QK-mode, [512,768)=V^T-mode ========
__global__ __launch_bounds__(256) void gemm_qkvt(const bf16_t* __restrict__ xb,
                                                 const bf16_t* __restrict__ WT,
                                                 bf16_t* __restrict__ Qb,
                                                 bf16_t* __restrict__ Kb,
                                                 bf16_t* __restrict__ Vt){
  const int K = DIM;
  __shared__ __align__(16) bf16_t As[128*32];
  __shared__ __align__(16) bf16_t Bs[128*32];
  const int bid = blockIdx.x, tid = threadIdx.x;
  const bool qkmode = bid < 512;
  int m0, n0;
  const bf16_t *Ap, *Bp;
  if(qkmode){ m0 = (bid>>4)*128;            n0 = (bid&15)*128;
              Ap = xb + (size_t)m0*K;       Bp = WT + (size_t)n0*K; }
  else      { int t = bid-512; m0 = (t>>5)*128; n0 = (t&31)*128;
              Ap = WT + (size_t)(2048+m0)*K; Bp = xb + (size_t)n0*K; }
  const int wave = tid>>6, lane = tid&63, l15 = lane&15, quad = lane>>4;
  const int wm = (wave>>1)*64, wn = (wave&1)*64;

  f32x4 acc[4][4];
  #pragma unroll
  for(int i=0;i<4;i++)
    #pragma unroll
    for(int j=0;j<4;j++) acc[i][j] = (f32x4){0.f,0.f,0.f,0.f};

  for(int k0=0; k0<K; k0+=32){
    int c = tid;
    gload16(Ap + (size_t)(c>>2)*K + k0 + (c&3)*8, &As[c*8]);
    gload16(Bp + (size_t)(c>>2)*K + k0 + (c&3)*8, &Bs[c*8]);
    c = tid + 256;
    gload16(Ap + (size_t)(c>>2)*K + k0 + (c&3)*8, &As[c*8]);
    gload16(Bp + (size_t)(c>>2)*K + k0 + (c&3)*8, &Bs[c*8]);
    __syncthreads();

    bf16x8 a[4], b[4];
    #pragma unroll
    for(int i=0;i<4;i++) a[i] = *(const bf16x8*)&As[(wm + i*16 + l15)*32 + quad*8];
    #pragma unroll
    for(int j=0;j<4;j++) b[j] = *(const bf16x8*)&Bs[(wn + j*16 + l15)*32 + quad*8];
    #pragma unroll
    for(int i=0;i<4;i++)
      #pragma unroll
      for(int j=0;j<4;j++)
        acc[i][j] = __builtin_amdgcn_mfma_f32_16x16x32_bf16(a[i], b[j], acc[i][j], 0,0,0);
    __syncthreads();
  }

  if(qkmode){
    #pragma unroll
    for(int j=0;j<4;j++){
      int col = n0 + wn + j*16 + l15;          // [0,2048)
      int which = col>>10, hc = col&1023, h = hc>>6, d = hc&63;
      bf16_t* dst = which ? Kb : Qb;
      #pragma unroll
      for(int i=0;i<4;i++){
        int m = m0 + wm + i*16 + quad*4;
        #pragma unroll
        for(int r=0;r<4;r++){
          int row = m + r;                      // b*1024 + n
          int bh = (row>>10)*HEADS + h, n = row&1023;
          dst[((size_t)bh*NN + n)*HD + d] = (bf16_t)acc[i][j][r];
        }
      }
    }
  } else {
    const int b = n0 >> 10;                     // token tile within one batch
    #pragma unroll
    for(int i=0;i<4;i++)
      #pragma unroll
      for(int j=0;j<4;j++){
        int vcol = m0 + wm + i*16 + quad*4;     // + r, within [0,1024)
        int ncol = (n0 & 1023) + wn + j*16 + l15;
        #pragma unroll
        for(int r=0;r<4;r++)
          Vt[((size_t)(b*1024 + vcol + r))*NN + ncol] = (bf16_t)acc[i][j][r];
      }
  }
}

// ---------------- per-token: z, zB (bf16), theta, entropy ----------------
__global__ __launch_bounds__(256) void token_kernel(
    const bf16_t* __restrict__ Qb, const float* __restrict__ Wgroup,
    const float* __restrict__ bgroup, const float* __restrict__ Wtheta,
    const float* __restrict__ btheta, const float* __restrict__ sigB,
    bf16_t* __restrict__ zb16, bf16_t* __restrict__ zBb16,
    float* __restrict__ thetaAll, float* __restrict__ entPart){
  const int wv = threadIdx.x>>6, lane = threadIdx.x&63;
  const int t = blockIdx.x*4 + wv;            // bh*1024 + n
  const int h = (t>>10)&15;
  float qd = (float)Qb[(size_t)t*HD + lane];

  float zl[8];
  #pragma unroll
  for(int c=0;c<8;c++){
    float p = qd * Wgroup[lane*NC + c];
    p += __shfl_xor(p,1);  p += __shfl_xor(p,2);  p += __shfl_xor(p,4);
    p += __shfl_xor(p,8);  p += __shfl_xor(p,16); p += __shfl_xor(p,32);
    zl[c] = p + bgroup[c];
  }
  float th = qd * Wtheta[lane];
  th += __shfl_xor(th,1);  th += __shfl_xor(th,2);  th += __shfl_xor(th,4);
  th += __shfl_xor(th,8);  th += __shfl_xor(th,16); th += __shfl_xor(th,32);
  th = fmaxf(th + btheta[0], 0.f);

  float mx = zl[0];
  #pragma unroll
  for(int c=1;c<8;c++) mx = fmaxf(mx, zl[c]);
  float ssum = 0.f;
  #pragma unroll
  for(int c=0;c<8;c++){ zl[c] = __expf(zl[c]-mx); ssum += zl[c]; }
  float inv = 1.f/ssum;
  float ent = 0.f;
  #pragma unroll
  for(int c=0;c<8;c++){ float z = zl[c]*inv; zl[c] = z; ent -= z*__logf(z + 1e-8f); }

  float zb[8];
  #pragma unroll
  for(int l=0;l<8;l++){
    float a = 0.f;
    #pragma unroll
    for(int k2=0;k2<8;k2++) a += zl[k2]*sigB[h*64 + k2*8 + l];
    zb[l] = a;
  }
  if(lane==0){
    bf16x8 zv, zbv;
    #pragma unroll
    for(int c=0;c<8;c++){ zv[c] = (bf16_t)zl[c]; zbv[c] = (bf16_t)zb[c]; }
    *(bf16x8*)&zb16[(size_t)t*8]  = zv;
    *(bf16x8*)&zBb16[(size_t)t*8] = zbv;
    thetaAll[t] = th;
  }

  __shared__ float es[4];
  if(lane==0) es[wv] = ent;
  __syncthreads();
  if(threadIdx.x==0) entPart[blockIdx.x] = es[0]+es[1]+es[2]+es[3];
}

// ------- fused flash attention + cp_bias (no-max softmax: logits bounded) -------
__global__ __launch_bounds__(256) void flash_kernel(
    const bf16_t* __restrict__ Qb, const bf16_t* __restrict__ Kb,
    const bf16_t* __restrict__ Vt, const bf16_t* __restrict__ zb16,
    const bf16_t* __restrict__ zBb16, const float* __restrict__ thetaAll,
    const float* __restrict__ cps_p, float* __restrict__ cp_out,
    bf16_t* __restrict__ attnO){
  const int bid = blockIdx.x;
  const int bh = bid & 63, qt = bid >> 6;     // XCD swizzle: same bh -> same XCD
  const int b = bh >> 4, h = bh & 15;
  const int tid = threadIdx.x;
  const int wave = tid>>6, lane = tid&63, l15 = lane&15, quad = lane>>4;

  __shared__ __align__(16) bf16_t Qs[64*64];
  __shared__ __align__(16) bf16_t Ks[64*64];
  __shared__ __align__(16) bf16_t Vs[64*64];   // [d][key]
  __shared__ __align__(16) bf16_t Ps[4][16*72];
  __shared__ float thAll[NN];                  // all thetas for this bh

  const float cps = cps_p[0];

  {
    const bf16_t* Qg = Qb + ((size_t)bh*NN + (size_t)qt*64)*HD;   // 8KB contiguous
    gload16(Qg + tid*8, &Qs[tid*8]);
    gload16(Qg + (tid+256)*8, &Qs[(tid+256)*8]);
    const float* tg = thetaAll + (size_t)bh*NN;
    float4 tv = *(const float4*)&tg[tid*4];
    *(float4*)&thAll[tid*4] = tv;
  }
  // zB_q as MFMA A-frag: k = quad*8+j, only quad 0 holds real (K=8) data
  bf16x8 aZ = (bf16x8)(bf16_t)0.f;
  if(quad==0)
    aZ = *(const bf16x8*)&zBb16[((size_t)bh*NN + qt*64 + wave*16 + l15)*8];
  __syncthreads();

  float th_i[4];
  #pragma unroll
  for(int r=0;r<4;r++)
    th_i[r] = thAll[qt*64 + wave*16 + quad*4 + r];

  bf16x8 aq0 = *(const bf16x8*)&Qs[(wave*16 + l15)*64 + quad*8];
  bf16x8 aq1 = *(const bf16x8*)&Qs[(wave*16 + l15)*64 + 32 + quad*8];

  float l_r[4] = {0.f,0.f,0.f,0.f};
  f32x4 o[4];
  #pragma unroll
  for(int dn=0;dn<4;dn++) o[dn] = (f32x4){0.f,0.f,0.f,0.f};

  for(int kt=0; kt<16; ++kt){
    // ---- async stage K,V ----
    const bf16_t* Kg = Kb + ((size_t)bh*NN + (size_t)kt*64)*HD;
    gload16(Kg + tid*8, &Ks[tid*8]);
    gload16(Kg + (tid+256)*8, &Ks[(tid+256)*8]);
    {
      int c = tid;
      gload16(Vt + (size_t)(bh*HD + (c>>3))*NN + kt*64 + (c&7)*8, &Vs[c*8]);
      c = tid + 256;
      gload16(Vt + (size_t)(bh*HD + (c>>3))*NN + kt*64 + (c&7)*8, &Vs[c*8]);
    }

    // ---- D = zB_q . z_k^T via MFMA (independent of LDS staging) ----
    f32x4 D[4];
    #pragma unroll
    for(int f=0;f<4;f++){
      bf16x8 bz = (bf16x8)(bf16_t)0.f;
      if(quad==0)
        bz = *(const bf16x8*)&zb16[((size_t)bh*NN + kt*64 + f*16 + l15)*8];
      D[f] = __builtin_amdgcn_mfma_f32_16x16x32_bf16(aZ, bz, (f32x4){0.f,0.f,0.f,0.f}, 0,0,0);
    }
    // ---- bias = cps*th_i*th_j*tanh(D), NT-store cp_bias ----
    float biasv[4][4];
    #pragma unroll
    for(int f=0;f<4;f++){
      int jloc = f*16 + l15;
      float thj = thAll[kt*64 + jloc];
      #pragma unroll
      for(int r=0;r<4;r++){
        float d = D[f][r];                       // |d| < 1 guaranteed
        float t2 = d*d;
        float p = -0.33333333f + t2*(0.13333333f + t2*(-0.05396825f));
        float tnh = d*(1.f + t2*p);
        float bv = cps * th_i[r] * thj * tnh;
        biasv[f][r] = bv;
        int irow = qt*64 + wave*16 + quad*4 + r;
        __builtin_nontemporal_store(bv,
            &cp_out[((size_t)bh*NN + irow)*NN + (size_t)kt*64 + jloc]);
      }
    }
    __syncthreads();   // staging visible

    // ---- S = Q K^T + bias ; P = exp(S) (no max: logits bounded ~|3|) ----
    f32x4 s[4];
    float rs[4] = {0.f,0.f,0.f,0.f};
    #pragma unroll
    for(int f=0;f<4;f++){
      f32x4 z4 = (f32x4){0.f,0.f,0.f,0.f};
      bf16x8 b0 = *(const bf16x8*)&Ks[(f*16 + l15)*64 + quad*8];
      bf16x8 b1 = *(const bf16x8*)&Ks[(f*16 + l15)*64 + 32 + quad*8];
      z4 = __builtin_amdgcn_mfma_f32_16x16x32_bf16(aq0, b0, z4, 0,0,0);
      z4 = __builtin_amdgcn_mfma_f32_16x16x32_bf16(aq1, b1, z4, 0,0,0);
      #pragma unroll
      for(int r=0;r<4;r++){
        float p = __expf(z4[r]*0.125f + biasv[f][r]);
        z4[r] = p;
        rs[r] += p;
      }
      s[f] = z4;
    }
    #pragma unroll
    for(int r=0;r<4;r++){
      float v = rs[r];
      v += __shfl_xor(v,1); v += __shfl_xor(v,2);
      v += __shfl_xor(v,4); v += __shfl_xor(v,8);
      l_r[r] += v;
    }

    // ---- P: C-layout -> A-layout via wave-private LDS ----
    #pragma unroll
    for(int f=0;f<4;f++)
      #pragma unroll
      for(int r=0;r<4;r++)
        Ps[wave][(quad*4+r)*72 + f*16 + l15] = (bf16_t)s[f][r];

    bf16x8 pa0 = *(const bf16x8*)&Ps[wave][l15*72 + quad*8];
    bf16x8 pa1 = *(const bf16x8*)&Ps[wave][l15*72 + 32 + quad*8];
    #pragma unroll
    for(int dn=0;dn<4;dn++){
      bf16x8 b0 = *(const bf16x8*)&Vs[(dn*16 + l15)*64 + quad*8];
      bf16x8 b1 = *(const bf16x8*)&Vs[(dn*16 + l15)*64 + 32 + quad*8];
      o[dn] = __builtin_amdgcn_mfma_f32_16x16x32_bf16(pa0, b0, o[dn], 0,0,0);
      o[dn] = __builtin_amdgcn_mfma_f32_16x16x32_bf16(pa1, b1, o[dn], 0,0,0);
    }
    __syncthreads();
  }

  #pragma unroll
  for(int r=0;r<4;r++){
    float inv = 1.f / l_r[r];
    int grow = qt*64 + wave*16 + quad*4 + r;
    #pragma unroll
    for(int dn=0;dn<4;dn++)
      attnO[((size_t)(b*NN + grow))*DIM + h*HD + dn*16 + l15] = (bf16_t)(o[dn][r]*inv);
  }
}

// ==== proj GEMM (512 tiles, 128x64) + entropy reduction in extra block 512 ====
__global__ __launch_bounds__(256) void gemm_proj_ent(const bf16_t* __restrict__ A,
                                                     const bf16_t* __restrict__ Bt,
                                                     float* __restrict__ C,
                                                     const float* __restrict__ bias,
                                                     const float* __restrict__ entPart,
                                                     float* __restrict__ outz){
  const int bid = blockIdx.x, tid = threadIdx.x;
  if(bid == 512){                      // entropy mean
    float s = 0.f;
    for(int i=tid; i<TOK/4; i+=256) s += entPart[i];
    s += __shfl_xor(s,1); s += __shfl_xor(s,2); s += __shfl_xor(s,4);
    s += __shfl_xor(s,8); s += __shfl_xor(s,16); s += __shfl_xor(s,32);
    __shared__ float ls[4];
    if((tid&63)==0) ls[tid>>6] = s;
    __syncthreads();
    if(tid==0) outz[0] = (ls[0]+ls[1]+ls[2]+ls[3]) * (1.0f/(float)TOK);
    return;
  }
  const int K = DIM, N = DIM;
  __shared__ __align__(16) bf16_t As[128*32];
  __shared__ __align__(16) bf16_t Bs[64*32];
  const int m0 = (bid>>4)*128, n0 = (bid&15)*64;
  const int wave = tid>>6, lane = tid&63, l15 = lane&15, quad = lane>>4;
  const int wm = (wave>>1)*64, wn = (wave&1)*32;

  f32x4 acc[4][2];
  #pragma unroll
  for(int i=0;i<4;i++)
    #pragma unroll
    for(int j=0;j<2;j++) acc[i][j] = (f32x4){0.f,0.f,0.f,0.f};

  for(int k0=0; k0<K; k0+=32){
    int c = tid;
    gload16(A  + (size_t)(m0 + (c>>2))*K + k0 + (c&3)*8, &As[c*8]);
    gload16(Bt + (size_t)(n0 + (c>>2))*K + k0 + (c&3)*8, &Bs[c*8]);
    c = tid + 256;
    gload16(A  + (size_t)(m0 + (c>>2))*K + k0 + (c&3)*8, &As[c*8]);
    __syncthreads();

    bf16x8 a[4], b[2];
    #pragma unroll
    for(int i=0;i<4;i++) a[i] = *(const bf16x8*)&As[(wm + i*16 + l15)*32 + quad*8];
    #pragma unroll
    for(int j=0;j<2;j++) b[j] = *(const bf16x8*)&Bs[(wn + j*16 + l15)*32 + quad*8];
    #pragma unroll
    for(int i=0;i<4;i++)
      #pragma unroll
      for(int j=0;j<2;j++)
        acc[i][j] = __builtin_amdgcn_mfma_f32_16x16x32_bf16(a[i], b[j], acc[i][j], 0,0,0);
    __syncthreads();
  }

  #pragma unroll
  for(int i=0;i<4;i++)
    #pragma unroll
    for(int j=0;j<2;j++){
      int row = m0 + wm + i*16 + quad*4;
      int col = n0 + wn + j*16 + l15;
      float bv = bias[col];
      #pragma unroll
      for(int r=0;r<4;r++)
        C[(size_t)(row+r)*N + col] = acc[i][j][r] + bv;
    }
}

// ---------------- launch ----------------
extern "C" void kernel_launch(void* const* d_in, const int* in_sizes, int n_in,
                              void* d_out, int out_size, void* d_ws, size_t ws_size,
                              hipStream_t stream){
  const float* x      = (const float*)d_in[0];
  const float* Wqkv   = (const float*)d_in[1];
  const float* Wproj  = (const float*)d_in[2];
  const float* bproj  = (const float*)d_in[3];
  const float* Wgroup = (const float*)d_in[4];
  const float* bgroup = (const float*)d_in[5];
  const float* Wtheta = (const float*)d_in[6];
  const float* btheta = (const float*)d_in[7];
  const float* affB   = (const float*)d_in[8];
  const float* cps    = (const float*)d_in[9];
  float* out = (float*)d_out;
  char* ws = (char*)d_ws;

  bf16_t* xb       = (bf16_t*)(ws);                       //  8 MB
  bf16_t* WqkvT    = (bf16_t*)(ws + (size_t)8*1048576);   //  6 MB
  bf16_t* WprojT   = (bf16_t*)(ws + (size_t)14*1048576);  //  2 MB
  bf16_t* Qb       = (bf16_t*)(ws + (size_t)16*1048576);  //  8 MB
  bf16_t* Kb       = (bf16_t*)(ws + (size_t)24*1048576);  //  8 MB
  bf16_t* Vt       = (bf16_t*)(ws + (size_t)32*1048576);  //  8 MB
  bf16_t* zb16     = (bf16_t*)(ws + (size_t)40*1048576);  //  1 MB
  bf16_t* zBb16    = (bf16_t*)(ws + (size_t)41*1048576);  //  1 MB
  float*  thetaAll = (float*) (ws + (size_t)42*1048576);  // .25 MB
  float*  entPart  = (float*) (ws + (size_t)43*1048576);  // 64 KB
  bf16_t* attnO    = (bf16_t*)(ws + (size_t)44*1048576);  //  8 MB
  float*  sigB     = (float*) (ws + (size_t)52*1048576);  //  4 KB

  prep_kernel<<<8193, 256, 0, stream>>>(x, Wqkv, Wproj, affB, xb, WqkvT, WprojT,
                                        sigB, out + OUT_OFF_Z);
  gemm_qkvt<<<768, 256, 0, stream>>>(xb, WqkvT, Qb, Kb, Vt);
  token_kernel<<<TOK/4, 256, 0, stream>>>(Qb, Wgroup, bgroup, Wtheta, btheta, sigB,
                                          zb16, zBb16, thetaAll, entPart);
  flash_kernel<<<1024, 256, 0, stream>>>(Qb, Kb, Vt, zb16, zBb16, thetaAll,
                                         cps, out + CP_OFF, attnO);
  gemm_proj_ent<<<513, 256, 0, stream>>>(attnO, WprojT, out, bproj,
                                         entPart, out + OUT_OFF_Z);
}

// Round 5
// 575.778 us; speedup vs baseline: 1.2016x; 1.2016x over previous
//
#include <hip/hip_runtime.h>
#include <stdint.h>

#define DIM 1024
#define HEADS 16
#define HD 64
#define NC 8
#define BB 4
#define NN 1024
#define ROWS (BB*NN)            // 4096
#define TOK (BB*HEADS*NN)       // 65536
#define OUT_OFF_Z (ROWS*DIM)    // 4194304
#define CP_OFF    (ROWS*DIM+3)  // 4194307

typedef __bf16 bf16_t;
typedef __attribute__((ext_vector_type(8))) __bf16 bf16x8;
typedef __attribute__((ext_vector_type(4))) __bf16 bf16x4;
typedef __attribute__((ext_vector_type(4))) float f32x4;

__device__ __forceinline__ void gload16(const void* g, void* l){
#if __has_builtin(__builtin_amdgcn_global_load_lds)
  __builtin_amdgcn_global_load_lds(
      (__attribute__((address_space(1))) void*)(g),
      (__attribute__((address_space(3))) void*)(l), 16, 0, 0);
#else
  *(uint4*)l = *(const uint4*)g;
#endif
}

__device__ __forceinline__ float tanh_poly(float d){  // |d| < 1
  float t2 = d*d;
  float p = -0.33333333f + t2*(0.13333333f + t2*(-0.05396825f));
  return d*(1.f + t2*p);
}

// ======== fused prep: x->bf16, Wqkv^T, Wproj^T, sigmoid(affB), zero scalars ========
__global__ __launch_bounds__(256) void prep_kernel(
    const float* __restrict__ x, const float* __restrict__ Wqkv,
    const float* __restrict__ Wproj, const float* __restrict__ affB,
    bf16_t* __restrict__ xb, bf16_t* __restrict__ WqkvT, bf16_t* __restrict__ WprojT,
    float* __restrict__ sigB, float* __restrict__ out_scalars){
  const int bid = blockIdx.x, tid = threadIdx.x;
  if(bid < 4096){                       // cvt x -> xb (4M elems, 1024/block)
    int i = (bid*256 + tid)*4;
    float4 v = *(const float4*)&x[i];
    bf16x4 o = {(bf16_t)v.x, (bf16_t)v.y, (bf16_t)v.z, (bf16_t)v.w};
    *(bf16x4*)&xb[i] = o;
    return;
  }
  if(bid < 8192){                       // transposes
    __shared__ float tile[32][33];
    const float* in; bf16_t* out; int K, N, bx, by;
    if(bid < 7168){ int t = bid-4096; in = Wqkv;  out = WqkvT;  K = 1024; N = 3072; bx = t%96; by = t/96; }
    else          { int t = bid-7168; in = Wproj; out = WprojT; K = 1024; N = 1024; bx = t%32; by = t/32; }
    int k0 = by*32, n0 = bx*32;
    int tx = tid & 31, ty = tid >> 5;   // 32 x 8
    #pragma unroll
    for(int r=ty; r<32; r+=8) tile[r][tx] = in[(size_t)(k0+r)*N + n0+tx];
    __syncthreads();
    #pragma unroll
    for(int r=ty; r<32; r+=8) out[(size_t)(n0+r)*K + k0+tx] = (bf16_t)tile[tx][r];
    return;
  }
  // small tail: sigB (1024) + zero 3 out scalars
  #pragma unroll
  for(int r=0;r<4;r++){
    int i = r*256 + tid;
    sigB[i] = 1.f/(1.f + __expf(-affB[i]));
  }
  if(tid < 3) out_scalars[tid] = 0.f;
}

// ======== merged QKV GEMM: 768 blocks; [0,512)=QK-mode, [512,768)=V^T-mode ========
// LDS swizzle (BK=32, 64B rows = 4x16B chunks): chunk s at row r holds global
// chunk s^((r>>1)&3)  -> ds_read_b128 2-way conflict (free).
__global__ __launch_bounds__(256) void gemm_qkvt(const bf16_t* __restrict__ xb,
                                                 const bf16_t* __restrict__ WT,
                                                 bf16_t* __restrict__ Qb,
                                                 bf16_t* __restrict__ Kb,
                                                 bf16_t* __restrict__ Vt){
  const int K = DIM;
  __shared__ __align__(16) bf16_t As[128*32];
  __shared__ __align__(16) bf16_t Bs[128*32];
  const int bid = blockIdx.x, tid = threadIdx.x;
  const bool qkmode = bid < 512;
  int m0, n0;
  const bf16_t *Ap, *Bp;
  if(qkmode){ m0 = (bid>>4)*128;            n0 = (bid&15)*128;
              Ap = xb + (size_t)m0*K;       Bp = WT + (size_t)n0*K; }
  else      { int t = bid-512; m0 = (t>>5)*128; n0 = (t&31)*128;
              Ap = WT + (size_t)(2048+m0)*K; Bp = xb + (size_t)n0*K; }
  const int wave = tid>>6, lane = tid&63, l15 = lane&15, quad = lane>>4;
  const int wm = (wave>>1)*64, wn = (wave&1)*64;

  f32x4 acc[4][4];
  #pragma unroll
  for(int i=0;i<4;i++)
    #pragma unroll
    for(int j=0;j<4;j++) acc[i][j] = (f32x4){0.f,0.f,0.f,0.f};

  for(int k0=0; k0<K; k0+=32){
    #pragma unroll
    for(int p=0;p<2;p++){
      int c = tid + p*256;
      int r = c>>2, s = c&3, xs = s ^ ((r>>1)&3);
      gload16(Ap + (size_t)r*K + k0 + xs*8, &As[c*8]);
      gload16(Bp + (size_t)r*K + k0 + xs*8, &Bs[c*8]);
    }
    __syncthreads();

    bf16x8 a[4], b[4];
    #pragma unroll
    for(int i=0;i<4;i++){
      int R = wm + i*16 + l15;
      a[i] = *(const bf16x8*)&As[R*32 + ((quad ^ ((R>>1)&3)))*8];
    }
    #pragma unroll
    for(int j=0;j<4;j++){
      int R = wn + j*16 + l15;
      b[j] = *(const bf16x8*)&Bs[R*32 + ((quad ^ ((R>>1)&3)))*8];
    }
    #pragma unroll
    for(int i=0;i<4;i++)
      #pragma unroll
      for(int j=0;j<4;j++)
        acc[i][j] = __builtin_amdgcn_mfma_f32_16x16x32_bf16(a[i], b[j], acc[i][j], 0,0,0);
    __syncthreads();
  }

  if(qkmode){
    #pragma unroll
    for(int j=0;j<4;j++){
      int col = n0 + wn + j*16 + l15;          // [0,2048)
      int which = col>>10, hc = col&1023, h = hc>>6, d = hc&63;
      bf16_t* dst = which ? Kb : Qb;
      #pragma unroll
      for(int i=0;i<4;i++){
        int m = m0 + wm + i*16 + quad*4;
        #pragma unroll
        for(int r=0;r<4;r++){
          int row = m + r;                      // b*1024 + n
          int bh = (row>>10)*HEADS + h, n = row&1023;
          dst[((size_t)bh*NN + n)*HD + d] = (bf16_t)acc[i][j][r];
        }
      }
    }
  } else {
    const int b = n0 >> 10;                     // token tile within one batch
    #pragma unroll
    for(int i=0;i<4;i++)
      #pragma unroll
      for(int j=0;j<4;j++){
        int vcol = m0 + wm + i*16 + quad*4;     // + r, within [0,1024)
        int ncol = (n0 & 1023) + wn + j*16 + l15;
        #pragma unroll
        for(int r=0;r<4;r++)
          Vt[((size_t)(b*1024 + vcol + r))*NN + ncol] = (bf16_t)acc[i][j][r];
      }
  }
}

// ---------------- per-token: z, zB (bf16), theta, entropy ----------------
__global__ __launch_bounds__(256) void token_kernel(
    const bf16_t* __restrict__ Qb, const float* __restrict__ Wgroup,
    const float* __restrict__ bgroup, const float* __restrict__ Wtheta,
    const float* __restrict__ btheta, const float* __restrict__ sigB,
    bf16_t* __restrict__ zb16, bf16_t* __restrict__ zBb16,
    float* __restrict__ thetaAll, float* __restrict__ entPart){
  const int wv = threadIdx.x>>6, lane = threadIdx.x&63;
  const int t = blockIdx.x*4 + wv;            // bh*1024 + n
  const int h = (t>>10)&15;
  float qd = (float)Qb[(size_t)t*HD + lane];

  float zl[8];
  #pragma unroll
  for(int c=0;c<8;c++){
    float p = qd * Wgroup[lane*NC + c];
    p += __shfl_xor(p,1);  p += __shfl_xor(p,2);  p += __shfl_xor(p,4);
    p += __shfl_xor(p,8);  p += __shfl_xor(p,16); p += __shfl_xor(p,32);
    zl[c] = p + bgroup[c];
  }
  float th = qd * Wtheta[lane];
  th += __shfl_xor(th,1);  th += __shfl_xor(th,2);  th += __shfl_xor(th,4);
  th += __shfl_xor(th,8);  th += __shfl_xor(th,16); th += __shfl_xor(th,32);
  th = fmaxf(th + btheta[0], 0.f);

  float mx = zl[0];
  #pragma unroll
  for(int c=1;c<8;c++) mx = fmaxf(mx, zl[c]);
  float ssum = 0.f;
  #pragma unroll
  for(int c=0;c<8;c++){ zl[c] = __expf(zl[c]-mx); ssum += zl[c]; }
  float inv = 1.f/ssum;
  float ent = 0.f;
  #pragma unroll
  for(int c=0;c<8;c++){ float z = zl[c]*inv; zl[c] = z; ent -= z*__logf(z + 1e-8f); }

  float zb[8];
  #pragma unroll
  for(int l=0;l<8;l++){
    float a = 0.f;
    #pragma unroll
    for(int k2=0;k2<8;k2++) a += zl[k2]*sigB[h*64 + k2*8 + l];
    zb[l] = a;
  }
  if(lane==0){
    bf16x8 zv, zbv;
    #pragma unroll
    for(int c=0;c<8;c++){ zv[c] = (bf16_t)zl[c]; zbv[c] = (bf16_t)zb[c]; }
    *(bf16x8*)&zb16[(size_t)t*8]  = zv;
    *(bf16x8*)&zBb16[(size_t)t*8] = zbv;
    thetaAll[t] = th;
  }

  __shared__ float es[4];
  if(lane==0) es[wv] = ent;
  __syncthreads();
  if(threadIdx.x==0) entPart[blockIdx.x] = es[0]+es[1]+es[2]+es[3];
}

// ======== cp_bias streaming writer: barrier-free, 256 MB regular stores ========
__global__ __launch_bounds__(256) void bias_kernel(
    const bf16_t* __restrict__ zb16, const bf16_t* __restrict__ zBb16,
    const float* __restrict__ thetaAll, const float* __restrict__ cps_p,
    float* __restrict__ cp_out){
  const int bid = blockIdx.x;
  const int bh = bid & 63, qt = bid >> 6;     // 64 q-rows per block
  const int tid = threadIdx.x;
  const int wave = tid>>6, lane = tid&63, l15 = lane&15, quad = lane>>4;
  __shared__ float thAll[NN];
  { float4 tv = *(const float4*)&thetaAll[(size_t)bh*NN + tid*4];
    *(float4*)&thAll[tid*4] = tv; }
  const float cps = cps_p[0];
  bf16x8 aZ = (bf16x8)(bf16_t)0.f;
  if(quad==0)
    aZ = *(const bf16x8*)&zBb16[((size_t)bh*NN + qt*64 + wave*16 + l15)*8];
  __syncthreads();
  float th_i[4];
  #pragma unroll
  for(int r=0;r<4;r++) th_i[r] = thAll[qt*64 + wave*16 + quad*4 + r];

  for(int kt=0; kt<16; ++kt){
    #pragma unroll
    for(int f=0;f<4;f++){
      bf16x8 bz = (bf16x8)(bf16_t)0.f;
      if(quad==0)
        bz = *(const bf16x8*)&zb16[((size_t)bh*NN + kt*64 + f*16 + l15)*8];
      f32x4 D = __builtin_amdgcn_mfma_f32_16x16x32_bf16(aZ, bz,
                  (f32x4){0.f,0.f,0.f,0.f}, 0,0,0);
      float thj = thAll[kt*64 + f*16 + l15];
      #pragma unroll
      for(int r=0;r<4;r++){
        float bv = cps * th_i[r] * thj * tanh_poly(D[r]);
        int irow = qt*64 + wave*16 + quad*4 + r;
        cp_out[((size_t)bh*NN + irow)*NN + (size_t)kt*64 + f*16 + l15] = bv;
      }
    }
  }
}

// ======== flash attention, 128 q-rows/block, swizzled LDS, no cp store ========
__global__ __launch_bounds__(256) void flash_kernel(
    const bf16_t* __restrict__ Qb, const bf16_t* __restrict__ Kb,
    const bf16_t* __restrict__ Vt, const bf16_t* __restrict__ zb16,
    const bf16_t* __restrict__ zBb16, const float* __restrict__ thetaAll,
    const float* __restrict__ cps_p, bf16_t* __restrict__ attnO){
  const int bid = blockIdx.x;
  const int bh = bid & 63, qt = bid >> 6;     // qt in [0,8): 128 q-rows
  const int b = bh >> 4, h = bh & 15;
  const int tid = threadIdx.x;
  const int wave = tid>>6, lane = tid&63, l15 = lane&15, quad = lane>>4;

  // 128B rows = 8x16B chunks; chunk s at row r holds global chunk s^(r&7)
  __shared__ __align__(16) bf16_t Qs[128*64];
  __shared__ __align__(16) bf16_t Ks[64*64];
  __shared__ __align__(16) bf16_t Vs[64*64];   // [d][key]
  __shared__ __align__(16) bf16_t Ps[4][16*72];
  __shared__ float thAll[NN];

  const float cps = cps_p[0];

  {
    const bf16_t* Qg = Qb + ((size_t)bh*NN + (size_t)qt*128)*HD;
    #pragma unroll
    for(int p=0;p<4;p++){
      int c = tid + p*256;
      int r = c>>3, xs = (c&7) ^ (r&7);
      gload16(Qg + r*64 + xs*8, &Qs[c*8]);
    }
    float4 tv = *(const float4*)&thetaAll[(size_t)bh*NN + tid*4];
    *(float4*)&thAll[tid*4] = tv;
  }
  bf16x8 aZ[2];
  #pragma unroll
  for(int qf=0;qf<2;qf++){
    aZ[qf] = (bf16x8)(bf16_t)0.f;
    if(quad==0)
      aZ[qf] = *(const bf16x8*)&zBb16[((size_t)bh*NN + qt*128 + wave*32 + qf*16 + l15)*8];
  }
  __syncthreads();

  float th_i[2][4];
  bf16x8 aq[2][2];
  #pragma unroll
  for(int qf=0;qf<2;qf++){
    int row = wave*32 + qf*16 + l15;
    aq[qf][0] = *(const bf16x8*)&Qs[row*64 + ((quad  ) ^ (row&7))*8];
    aq[qf][1] = *(const bf16x8*)&Qs[row*64 + ((quad+4) ^ (row&7))*8];
    #pragma unroll
    for(int r=0;r<4;r++)
      th_i[qf][r] = thAll[qt*128 + wave*32 + qf*16 + quad*4 + r];
  }

  float l_r[2][4] = {{0.f,0.f,0.f,0.f},{0.f,0.f,0.f,0.f}};
  f32x4 o[2][4];
  #pragma unroll
  for(int qf=0;qf<2;qf++)
    #pragma unroll
    for(int dn=0;dn<4;dn++) o[qf][dn] = (f32x4){0.f,0.f,0.f,0.f};

  for(int kt=0; kt<16; ++kt){
    // ---- async stage K,V (swizzled) ----
    const bf16_t* Kg = Kb + ((size_t)bh*NN + (size_t)kt*64)*HD;
    #pragma unroll
    for(int p=0;p<2;p++){
      int c = tid + p*256;
      int r = c>>3, xs = (c&7) ^ (r&7);
      gload16(Kg + r*64 + xs*8, &Ks[c*8]);
    }
    #pragma unroll
    for(int p=0;p<2;p++){
      int c = tid + p*256;
      int r = c>>3, xs = (c&7) ^ (r&7);
      gload16(Vt + (size_t)(bh*HD + r)*NN + kt*64 + xs*8, &Vs[c*8]);
    }

    // ---- bias logits (uses only global zb16 + thAll; fills load shadow) ----
    float biasv[2][4][4];
    #pragma unroll
    for(int f=0;f<4;f++){
      bf16x8 bz = (bf16x8)(bf16_t)0.f;
      if(quad==0)
        bz = *(const bf16x8*)&zb16[((size_t)bh*NN + kt*64 + f*16 + l15)*8];
      float thj = thAll[kt*64 + f*16 + l15];
      #pragma unroll
      for(int qf=0;qf<2;qf++){
        f32x4 D = __builtin_amdgcn_mfma_f32_16x16x32_bf16(aZ[qf], bz,
                    (f32x4){0.f,0.f,0.f,0.f}, 0,0,0);
        #pragma unroll
        for(int r=0;r<4;r++)
          biasv[qf][f][r] = cps * th_i[qf][r] * thj * tanh_poly(D[r]);
      }
    }
    __syncthreads();   // staging visible

    #pragma unroll
    for(int qf=0;qf<2;qf++){
      // ---- S = Q K^T + bias ; P = exp(S) (logits bounded, no max) ----
      f32x4 s[4];
      float rs[4] = {0.f,0.f,0.f,0.f};
      #pragma unroll
      for(int f=0;f<4;f++){
        int row = f*16 + l15;
        f32x4 z4 = (f32x4){0.f,0.f,0.f,0.f};
        bf16x8 b0 = *(const bf16x8*)&Ks[row*64 + ((quad  ) ^ (row&7))*8];
        bf16x8 b1 = *(const bf16x8*)&Ks[row*64 + ((quad+4) ^ (row&7))*8];
        z4 = __builtin_amdgcn_mfma_f32_16x16x32_bf16(aq[qf][0], b0, z4, 0,0,0);
        z4 = __builtin_amdgcn_mfma_f32_16x16x32_bf16(aq[qf][1], b1, z4, 0,0,0);
        #pragma unroll
        for(int r=0;r<4;r++){
          float p = __expf(z4[r]*0.125f + biasv[qf][f][r]);
          z4[r] = p;
          rs[r] += p;
        }
        s[f] = z4;
      }
      #pragma unroll
      for(int r=0;r<4;r++){
        float v = rs[r];
        v += __shfl_xor(v,1); v += __shfl_xor(v,2);
        v += __shfl_xor(v,4); v += __shfl_xor(v,8);
        l_r[qf][r] += v;
      }

      // ---- P: C-layout -> A-layout via wave-private LDS (72-stride) ----
      #pragma unroll
      for(int f=0;f<4;f++)
        #pragma unroll
        for(int r=0;r<4;r++)
          Ps[wave][(quad*4+r)*72 + f*16 + l15] = (bf16_t)s[f][r];

      bf16x8 pa0 = *(const bf16x8*)&Ps[wave][l15*72 + quad*8];
      bf16x8 pa1 = *(const bf16x8*)&Ps[wave][l15*72 + 32 + quad*8];
      #pragma unroll
      for(int dn=0;dn<4;dn++){
        int row = dn*16 + l15;
        bf16x8 b0 = *(const bf16x8*)&Vs[row*64 + ((quad  ) ^ (row&7))*8];
        bf16x8 b1 = *(const bf16x8*)&Vs[row*64 + ((quad+4) ^ (row&7))*8];
        o[qf][dn] = __builtin_amdgcn_mfma_f32_16x16x32_bf16(pa0, b0, o[qf][dn], 0,0,0);
        o[qf][dn] = __builtin_amdgcn_mfma_f32_16x16x32_bf16(pa1, b1, o[qf][dn], 0,0,0);
      }
    }
    __syncthreads();
  }

  #pragma unroll
  for(int qf=0;qf<2;qf++)
    #pragma unroll
    for(int r=0;r<4;r++){
      float inv = 1.f / l_r[qf][r];
      int grow = qt*128 + wave*32 + qf*16 + quad*4 + r;
      #pragma unroll
      for(int dn=0;dn<4;dn++)
        attnO[((size_t)(b*NN + grow))*DIM + h*HD + dn*16 + l15] = (bf16_t)(o[qf][dn][r]*inv);
    }
}

// ==== proj GEMM (512 tiles, 128x64) + entropy reduction in extra block 512 ====
__global__ __launch_bounds__(256) void gemm_proj_ent(const bf16_t* __restrict__ A,
                                                     const bf16_t* __restrict__ Bt,
                                                     float* __restrict__ C,
                                                     const float* __restrict__ bias,
                                                     const float* __restrict__ entPart,
                                                     float* __restrict__ outz){
  const int bid = blockIdx.x, tid = threadIdx.x;
  if(bid == 512){                      // entropy mean
    float s = 0.f;
    for(int i=tid; i<TOK/4; i+=256) s += entPart[i];
    s += __shfl_xor(s,1); s += __shfl_xor(s,2); s += __shfl_xor(s,4);
    s += __shfl_xor(s,8); s += __shfl_xor(s,16); s += __shfl_xor(s,32);
    __shared__ float ls[4];
    if((tid&63)==0) ls[tid>>6] = s;
    __syncthreads();
    if(tid==0) outz[0] = (ls[0]+ls[1]+ls[2]+ls[3]) * (1.0f/(float)TOK);
    return;
  }
  const int K = DIM, N = DIM;
  __shared__ __align__(16) bf16_t As[128*32];
  __shared__ __align__(16) bf16_t Bs[64*32];
  const int m0 = (bid>>4)*128, n0 = (bid&15)*64;
  const int wave = tid>>6, lane = tid&63, l15 = lane&15, quad = lane>>4;
  const int wm = (wave>>1)*64, wn = (wave&1)*32;

  f32x4 acc[4][2];
  #pragma unroll
  for(int i=0;i<4;i++)
    #pragma unroll
    for(int j=0;j<2;j++) acc[i][j] = (f32x4){0.f,0.f,0.f,0.f};

  for(int k0=0; k0<K; k0+=32){
    {
      int c = tid;
      int r = c>>2, s = c&3, xs = s ^ ((r>>1)&3);
      gload16(A  + (size_t)(m0 + r)*K + k0 + xs*8, &As[c*8]);
      gload16(Bt + (size_t)(n0 + r)*K + k0 + xs*8, &Bs[c*8]);
      c = tid + 256;
      r = c>>2; s = c&3; xs = s ^ ((r>>1)&3);
      gload16(A  + (size_t)(m0 + r)*K + k0 + xs*8, &As[c*8]);
    }
    __syncthreads();

    bf16x8 a[4], b[2];
    #pragma unroll
    for(int i=0;i<4;i++){
      int R = wm + i*16 + l15;
      a[i] = *(const bf16x8*)&As[R*32 + ((quad ^ ((R>>1)&3)))*8];
    }
    #pragma unroll
    for(int j=0;j<2;j++){
      int R = wn + j*16 + l15;
      b[j] = *(const bf16x8*)&Bs[R*32 + ((quad ^ ((R>>1)&3)))*8];
    }
    #pragma unroll
    for(int i=0;i<4;i++)
      #pragma unroll
      for(int j=0;j<2;j++)
        acc[i][j] = __builtin_amdgcn_mfma_f32_16x16x32_bf16(a[i], b[j], acc[i][j], 0,0,0);
    __syncthreads();
  }

  #pragma unroll
  for(int i=0;i<4;i++)
    #pragma unroll
    for(int j=0;j<2;j++){
      int row = m0 + wm + i*16 + quad*4;
      int col = n0 + wn + j*16 + l15;
      float bv = bias[col];
      #pragma unroll
      for(int r=0;r<4;r++)
        C[(size_t)(row+r)*N + col] = acc[i][j][r] + bv;
    }
}

// ---------------- launch ----------------
extern "C" void kernel_launch(void* const* d_in, const int* in_sizes, int n_in,
                              void* d_out, int out_size, void* d_ws, size_t ws_size,
                              hipStream_t stream){
  const float* x      = (const float*)d_in[0];
  const float* Wqkv   = (const float*)d_in[1];
  const float* Wproj  = (const float*)d_in[2];
  const float* bproj  = (const float*)d_in[3];
  const float* Wgroup = (const float*)d_in[4];
  const float* bgroup = (const float*)d_in[5];
  const float* Wtheta = (const float*)d_in[6];
  const float* btheta = (const float*)d_in[7];
  const float* affB   = (const float*)d_in[8];
  const float* cps    = (const float*)d_in[9];
  float* out = (float*)d_out;
  char* ws = (char*)d_ws;

  bf16_t* xb       = (bf16_t*)(ws);                       //  8 MB
  bf16_t* WqkvT    = (bf16_t*)(ws + (size_t)8*1048576);   //  6 MB
  bf16_t* WprojT   = (bf16_t*)(ws + (size_t)14*1048576);  //  2 MB
  bf16_t* Qb       = (bf16_t*)(ws + (size_t)16*1048576);  //  8 MB
  bf16_t* Kb       = (bf16_t*)(ws + (size_t)24*1048576);  //  8 MB
  bf16_t* Vt       = (bf16_t*)(ws + (size_t)32*1048576);  //  8 MB
  bf16_t* zb16     = (bf16_t*)(ws + (size_t)40*1048576);  //  1 MB
  bf16_t* zBb16    = (bf16_t*)(ws + (size_t)41*1048576);  //  1 MB
  float*  thetaAll = (float*) (ws + (size_t)42*1048576);  // .25 MB
  float*  entPart  = (float*) (ws + (size_t)43*1048576);  // 64 KB
  bf16_t* attnO    = (bf16_t*)(ws + (size_t)44*1048576);  //  8 MB
  float*  sigB     = (float*) (ws + (size_t)52*1048576);  //  4 KB

  prep_kernel<<<8193, 256, 0, stream>>>(x, Wqkv, Wproj, affB, xb, WqkvT, WprojT,
                                        sigB, out + OUT_OFF_Z);
  gemm_qkvt<<<768, 256, 0, stream>>>(xb, WqkvT, Qb, Kb, Vt);
  token_kernel<<<TOK/4, 256, 0, stream>>>(Qb, Wgroup, bgroup, Wtheta, btheta, sigB,
                                          zb16, zBb16, thetaAll, entPart);
  bias_kernel<<<1024, 256, 0, stream>>>(zb16, zBb16, thetaAll, cps, out + CP_OFF);
  flash_kernel<<<512, 256, 0, stream>>>(Qb, Kb, Vt, zb16, zBb16, thetaAll,
                                        cps, attnO);
  gemm_proj_ent<<<513, 256, 0, stream>>>(attnO, WprojT, out, bproj,
                                         entPart, out + OUT_OFF_Z);
}

// Round 6
// 478.477 us; speedup vs baseline: 1.4460x; 1.2034x over previous
//
#include <hip/hip_runtime.h>
#include <stdint.h>

#define DIM 1024
#define HEADS 16
#define HD 64
#define NC 8
#define BB 4
#define NN 1024
#define ROWS (BB*NN)            // 4096
#define TOK (BB*HEADS*NN)       // 65536
#define OUT_OFF_Z (ROWS*DIM)    // 4194304
#define CP_OFF    (ROWS*DIM+3)  // 4194307

typedef __bf16 bf16_t;
typedef __attribute__((ext_vector_type(8))) __bf16 bf16x8;
typedef __attribute__((ext_vector_type(4))) __bf16 bf16x4;
typedef __attribute__((ext_vector_type(4))) float f32x4;

__device__ __forceinline__ void gload16(const void* g, void* l){
#if __has_builtin(__builtin_amdgcn_global_load_lds)
  __builtin_amdgcn_global_load_lds(
      (__attribute__((address_space(1))) void*)(g),
      (__attribute__((address_space(3))) void*)(l), 16, 0, 0);
#else
  *(uint4*)l = *(const uint4*)g;
#endif
}

__device__ __forceinline__ float tanh_poly(float d){  // |d| < 1
  float t2 = d*d;
  float p = -0.33333333f + t2*(0.13333333f + t2*(-0.05396825f));
  return d*(1.f + t2*p);
}

// ======== fused prep: x->bf16, Wqkv^T, Wproj^T, sigmoid(affB), zero scalars ========
__global__ __launch_bounds__(256) void prep_kernel(
    const float* __restrict__ x, const float* __restrict__ Wqkv,
    const float* __restrict__ Wproj, const float* __restrict__ affB,
    bf16_t* __restrict__ xb, bf16_t* __restrict__ WqkvT, bf16_t* __restrict__ WprojT,
    float* __restrict__ sigB, float* __restrict__ out_scalars){
  const int bid = blockIdx.x, tid = threadIdx.x;
  if(bid < 4096){                       // cvt x -> xb (4M elems, 1024/block)
    int i = (bid*256 + tid)*4;
    float4 v = *(const float4*)&x[i];
    bf16x4 o = {(bf16_t)v.x, (bf16_t)v.y, (bf16_t)v.z, (bf16_t)v.w};
    *(bf16x4*)&xb[i] = o;
    return;
  }
  if(bid < 8192){                       // transposes
    __shared__ float tile[32][33];
    const float* in; bf16_t* out; int K, N, bx, by;
    if(bid < 7168){ int t = bid-4096; in = Wqkv;  out = WqkvT;  K = 1024; N = 3072; bx = t%96; by = t/96; }
    else          { int t = bid-7168; in = Wproj; out = WprojT; K = 1024; N = 1024; bx = t%32; by = t/32; }
    int k0 = by*32, n0 = bx*32;
    int tx = tid & 31, ty = tid >> 5;   // 32 x 8
    #pragma unroll
    for(int r=ty; r<32; r+=8) tile[r][tx] = in[(size_t)(k0+r)*N + n0+tx];
    __syncthreads();
    #pragma unroll
    for(int r=ty; r<32; r+=8) out[(size_t)(n0+r)*K + k0+tx] = (bf16_t)tile[tx][r];
    return;
  }
  // small tail: sigB (1024) + zero 3 out scalars
  #pragma unroll
  for(int r=0;r<4;r++){
    int i = r*256 + tid;
    sigB[i] = 1.f/(1.f + __expf(-affB[i]));
  }
  if(tid < 3) out_scalars[tid] = 0.f;
}

// ======== merged QKV GEMM: 768 blocks; [0,512)=QK-mode, [512,768)=V^T-mode ========
__global__ __launch_bounds__(256) void gemm_qkvt(const bf16_t* __restrict__ xb,
                                                 const bf16_t* __restrict__ WT,
                                                 bf16_t* __restrict__ Qb,
                                                 bf16_t* __restrict__ Kb,
                                                 bf16_t* __restrict__ Vt){
  const int K = DIM;
  __shared__ __align__(16) bf16_t As[128*32];
  __shared__ __align__(16) bf16_t Bs[128*32];
  const int bid = blockIdx.x, tid = threadIdx.x;
  const bool qkmode = bid < 512;
  int m0, n0;
  const bf16_t *Ap, *Bp;
  if(qkmode){ m0 = (bid>>4)*128;            n0 = (bid&15)*128;
              Ap = xb + (size_t)m0*K;       Bp = WT + (size_t)n0*K; }
  else      { int t = bid-512; m0 = (t>>5)*128; n0 = (t&31)*128;
              Ap = WT + (size_t)(2048+m0)*K; Bp = xb + (size_t)n0*K; }
  const int wave = tid>>6, lane = tid&63, l15 = lane&15, quad = lane>>4;
  const int wm = (wave>>1)*64, wn = (wave&1)*64;

  f32x4 acc[4][4];
  #pragma unroll
  for(int i=0;i<4;i++)
    #pragma unroll
    for(int j=0;j<4;j++) acc[i][j] = (f32x4){0.f,0.f,0.f,0.f};

  for(int k0=0; k0<K; k0+=32){
    #pragma unroll
    for(int p=0;p<2;p++){
      int c = tid + p*256;
      int r = c>>2, s = c&3, xs = s ^ ((r>>1)&3);
      gload16(Ap + (size_t)r*K + k0 + xs*8, &As[c*8]);
      gload16(Bp + (size_t)r*K + k0 + xs*8, &Bs[c*8]);
    }
    __syncthreads();

    bf16x8 a[4], b[4];
    #pragma unroll
    for(int i=0;i<4;i++){
      int R = wm + i*16 + l15;
      a[i] = *(const bf16x8*)&As[R*32 + ((quad ^ ((R>>1)&3)))*8];
    }
    #pragma unroll
    for(int j=0;j<4;j++){
      int R = wn + j*16 + l15;
      b[j] = *(const bf16x8*)&Bs[R*32 + ((quad ^ ((R>>1)&3)))*8];
    }
    #pragma unroll
    for(int i=0;i<4;i++)
      #pragma unroll
      for(int j=0;j<4;j++)
        acc[i][j] = __builtin_amdgcn_mfma_f32_16x16x32_bf16(a[i], b[j], acc[i][j], 0,0,0);
    __syncthreads();
  }

  if(qkmode){
    #pragma unroll
    for(int j=0;j<4;j++){
      int col = n0 + wn + j*16 + l15;          // [0,2048)
      int which = col>>10, hc = col&1023, h = hc>>6, d = hc&63;
      bf16_t* dst = which ? Kb : Qb;
      #pragma unroll
      for(int i=0;i<4;i++){
        int m = m0 + wm + i*16 + quad*4;
        #pragma unroll
        for(int r=0;r<4;r++){
          int row = m + r;                      // b*1024 + n
          int bh = (row>>10)*HEADS + h, n = row&1023;
          dst[((size_t)bh*NN + n)*HD + d] = (bf16_t)acc[i][j][r];
        }
      }
    }
  } else {
    const int b = n0 >> 10;                     // token tile within one batch
    #pragma unroll
    for(int i=0;i<4;i++)
      #pragma unroll
      for(int j=0;j<4;j++){
        int vcol = m0 + wm + i*16 + quad*4;     // + r, within [0,1024)
        int ncol = (n0 & 1023) + wn + j*16 + l15;
        #pragma unroll
        for(int r=0;r<4;r++)
          Vt[((size_t)(b*1024 + vcol + r))*NN + ncol] = (bf16_t)acc[i][j][r];
      }
  }
}

// ======== token kernel: thread-per-token (256 blocks, h block-uniform) ========
__global__ __launch_bounds__(256) void token_kernel(
    const bf16_t* __restrict__ Qb, const float* __restrict__ Wgroup,
    const float* __restrict__ bgroup, const float* __restrict__ Wtheta,
    const float* __restrict__ btheta, const float* __restrict__ sigB,
    bf16_t* __restrict__ zb16, bf16_t* __restrict__ zBb16,
    float* __restrict__ thetaAll, float* __restrict__ entPart){
  const int bid = blockIdx.x, tid = threadIdx.x;
  const int t = bid*256 + tid;                // token id; block spans one bh
  const int h = (t>>10)&15;
  __shared__ float Wg[64][NC];                // 2KB
  __shared__ float Wt[64];
  __shared__ float sB[64];
  __shared__ float bg[NC];
  if(tid < 64){
    #pragma unroll
    for(int c=0;c<NC;c++) Wg[tid][c] = Wgroup[tid*NC + c];
    Wt[tid] = Wtheta[tid];
    sB[tid] = sigB[h*64 + tid];
  }
  if(tid < NC) bg[tid] = bgroup[tid];
  __syncthreads();

  float zl[8] = {0,0,0,0,0,0,0,0};
  float th = 0.f;
  const bf16_t* qrow = Qb + (size_t)t*HD;
  #pragma unroll
  for(int v=0; v<8; v++){
    bf16x8 qv = *(const bf16x8*)&qrow[v*8];
    #pragma unroll
    for(int e=0;e<8;e++){
      float qd = (float)qv[e];
      int d = v*8+e;
      #pragma unroll
      for(int c=0;c<8;c++) zl[c] += qd * Wg[d][c];
      th += qd * Wt[d];
    }
  }
  th = fmaxf(th + btheta[0], 0.f);
  #pragma unroll
  for(int c=0;c<8;c++) zl[c] += bg[c];

  float mx = zl[0];
  #pragma unroll
  for(int c=1;c<8;c++) mx = fmaxf(mx, zl[c]);
  float ssum = 0.f;
  #pragma unroll
  for(int c=0;c<8;c++){ zl[c] = __expf(zl[c]-mx); ssum += zl[c]; }
  float inv = 1.f/ssum;
  float ent = 0.f;
  #pragma unroll
  for(int c=0;c<8;c++){ float z = zl[c]*inv; zl[c] = z; ent -= z*__logf(z + 1e-8f); }

  float zb[8];
  #pragma unroll
  for(int l=0;l<8;l++){
    float a = 0.f;
    #pragma unroll
    for(int k2=0;k2<8;k2++) a += zl[k2]*sB[k2*8 + l];
    zb[l] = a;
  }
  bf16x8 zv, zbv;
  #pragma unroll
  for(int c=0;c<8;c++){ zv[c] = (bf16_t)zl[c]; zbv[c] = (bf16_t)zb[c]; }
  *(bf16x8*)&zb16[(size_t)t*8]  = zv;
  *(bf16x8*)&zBb16[(size_t)t*8] = zbv;
  thetaAll[t] = th;

  // entropy partial: wave reduce -> LDS -> block sum
  ent += __shfl_xor(ent,1);  ent += __shfl_xor(ent,2);  ent += __shfl_xor(ent,4);
  ent += __shfl_xor(ent,8);  ent += __shfl_xor(ent,16); ent += __shfl_xor(ent,32);
  __shared__ float es[4];
  if((tid&63)==0) es[tid>>6] = ent;
  __syncthreads();
  if(tid==0) entPart[bid] = es[0]+es[1]+es[2]+es[3];
}

// ======== merged attention dispatch: [0,512)=flash, [512,1536)=bias writer ========
__global__ __launch_bounds__(256) void attn_kernel(
    const bf16_t* __restrict__ Qb, const bf16_t* __restrict__ Kb,
    const bf16_t* __restrict__ Vt, const bf16_t* __restrict__ zb16,
    const bf16_t* __restrict__ zBb16, const float* __restrict__ thetaAll,
    const float* __restrict__ cps_p, float* __restrict__ cp_out,
    bf16_t* __restrict__ attnO){
  const int bid = blockIdx.x;
  const int tid = threadIdx.x;
  const int wave = tid>>6, lane = tid&63, l15 = lane&15, quad = lane>>4;
  const float cps = cps_p[0];

  // 128B rows = 8x16B chunks; chunk s at row r holds global chunk s^(r&7)
  __shared__ __align__(16) bf16_t Qs[128*64];
  __shared__ __align__(16) bf16_t Ks[64*64];
  __shared__ __align__(16) bf16_t Vs[64*64];   // [d][key]
  __shared__ __align__(16) bf16_t Ps[4][16*72];
  __shared__ float thAll[NN];

  if(bid >= 512){
    // ---------------- bias writer: 64 q-rows/block, barrier-free stream ----------------
    const int b2 = bid - 512;
    const int bh = b2 & 63, qt = b2 >> 6;
    { float4 tv = *(const float4*)&thetaAll[(size_t)bh*NN + tid*4];
      *(float4*)&thAll[tid*4] = tv; }
    bf16x8 aZ = (bf16x8)(bf16_t)0.f;
    if(quad==0)
      aZ = *(const bf16x8*)&zBb16[((size_t)bh*NN + qt*64 + wave*16 + l15)*8];
    __syncthreads();
    float th_i[4];
    #pragma unroll
    for(int r=0;r<4;r++) th_i[r] = thAll[qt*64 + wave*16 + quad*4 + r];

    for(int kt=0; kt<16; ++kt){
      #pragma unroll
      for(int f=0;f<4;f++){
        bf16x8 bz = (bf16x8)(bf16_t)0.f;
        if(quad==0)
          bz = *(const bf16x8*)&zb16[((size_t)bh*NN + kt*64 + f*16 + l15)*8];
        f32x4 D = __builtin_amdgcn_mfma_f32_16x16x32_bf16(aZ, bz,
                    (f32x4){0.f,0.f,0.f,0.f}, 0,0,0);
        float thj = thAll[kt*64 + f*16 + l15];
        #pragma unroll
        for(int r=0;r<4;r++){
          float bv = cps * th_i[r] * thj * tanh_poly(D[r]);
          int irow = qt*64 + wave*16 + quad*4 + r;
          cp_out[((size_t)bh*NN + irow)*NN + (size_t)kt*64 + f*16 + l15] = bv;
        }
      }
    }
    return;
  }

  // ---------------- flash: 128 q-rows/block ----------------
  const int bh = bid & 63, qt = bid >> 6;     // qt in [0,4): XCD swizzle on bh
  const int b = bh >> 4, h = bh & 15;

  {
    const bf16_t* Qg = Qb + ((size_t)bh*NN + (size_t)qt*128)*HD;
    #pragma unroll
    for(int p=0;p<4;p++){
      int c = tid + p*256;
      int r = c>>3, xs = (c&7) ^ (r&7);
      gload16(Qg + r*64 + xs*8, &Qs[c*8]);
    }
    float4 tv = *(const float4*)&thetaAll[(size_t)bh*NN + tid*4];
    *(float4*)&thAll[tid*4] = tv;
  }
  bf16x8 aZ[2];
  #pragma unroll
  for(int qf=0;qf<2;qf++){
    aZ[qf] = (bf16x8)(bf16_t)0.f;
    if(quad==0)
      aZ[qf] = *(const bf16x8*)&zBb16[((size_t)bh*NN + qt*128 + wave*32 + qf*16 + l15)*8];
  }
  __syncthreads();

  float th_i[2][4];
  bf16x8 aq[2][2];
  #pragma unroll
  for(int qf=0;qf<2;qf++){
    int row = wave*32 + qf*16 + l15;
    aq[qf][0] = *(const bf16x8*)&Qs[row*64 + ((quad  ) ^ (row&7))*8];
    aq[qf][1] = *(const bf16x8*)&Qs[row*64 + ((quad+4) ^ (row&7))*8];
    #pragma unroll
    for(int r=0;r<4;r++)
      th_i[qf][r] = thAll[qt*128 + wave*32 + qf*16 + quad*4 + r];
  }

  float l_r[2][4] = {{0.f,0.f,0.f,0.f},{0.f,0.f,0.f,0.f}};
  f32x4 o[2][4];
  #pragma unroll
  for(int qf=0;qf<2;qf++)
    #pragma unroll
    for(int dn=0;dn<4;dn++) o[qf][dn] = (f32x4){0.f,0.f,0.f,0.f};

  for(int kt=0; kt<16; ++kt){
    // ---- async stage K,V (swizzled) ----
    const bf16_t* Kg = Kb + ((size_t)bh*NN + (size_t)kt*64)*HD;
    #pragma unroll
    for(int p=0;p<2;p++){
      int c = tid + p*256;
      int r = c>>3, xs = (c&7) ^ (r&7);
      gload16(Kg + r*64 + xs*8, &Ks[c*8]);
    }
    #pragma unroll
    for(int p=0;p<2;p++){
      int c = tid + p*256;
      int r = c>>3, xs = (c&7) ^ (r&7);
      gload16(Vt + (size_t)(bh*HD + r)*NN + kt*64 + xs*8, &Vs[c*8]);
    }

    // ---- bias logits (fills the staging-load shadow) ----
    float biasv[2][4][4];
    #pragma unroll
    for(int f=0;f<4;f++){
      bf16x8 bz = (bf16x8)(bf16_t)0.f;
      if(quad==0)
        bz = *(const bf16x8*)&zb16[((size_t)bh*NN + kt*64 + f*16 + l15)*8];
      float thj = thAll[kt*64 + f*16 + l15];
      #pragma unroll
      for(int qf=0;qf<2;qf++){
        f32x4 D = __builtin_amdgcn_mfma_f32_16x16x32_bf16(aZ[qf], bz,
                    (f32x4){0.f,0.f,0.f,0.f}, 0,0,0);
        #pragma unroll
        for(int r=0;r<4;r++)
          biasv[qf][f][r] = cps * th_i[qf][r] * thj * tanh_poly(D[r]);
      }
    }
    __syncthreads();   // staging visible

    #pragma unroll
    for(int qf=0;qf<2;qf++){
      // ---- S = Q K^T + bias ; P = exp(S) (logits bounded, no max) ----
      f32x4 s[4];
      float rs[4] = {0.f,0.f,0.f,0.f};
      #pragma unroll
      for(int f=0;f<4;f++){
        int row = f*16 + l15;
        f32x4 z4 = (f32x4){0.f,0.f,0.f,0.f};
        bf16x8 b0 = *(const bf16x8*)&Ks[row*64 + ((quad  ) ^ (row&7))*8];
        bf16x8 b1 = *(const bf16x8*)&Ks[row*64 + ((quad+4) ^ (row&7))*8];
        z4 = __builtin_amdgcn_mfma_f32_16x16x32_bf16(aq[qf][0], b0, z4, 0,0,0);
        z4 = __builtin_amdgcn_mfma_f32_16x16x32_bf16(aq[qf][1], b1, z4, 0,0,0);
        #pragma unroll
        for(int r=0;r<4;r++){
          float p = __expf(z4[r]*0.125f + biasv[qf][f][r]);
          z4[r] = p;
          rs[r] += p;
        }
        s[f] = z4;
      }
      #pragma unroll
      for(int r=0;r<4;r++){
        float v = rs[r];
        v += __shfl_xor(v,1); v += __shfl_xor(v,2);
        v += __shfl_xor(v,4); v += __shfl_xor(v,8);
        l_r[qf][r] += v;
      }

      // ---- P: C-layout -> A-layout via wave-private LDS (72-stride) ----
      #pragma unroll
      for(int f=0;f<4;f++)
        #pragma unroll
        for(int r=0;r<4;r++)
          Ps[wave][(quad*4+r)*72 + f*16 + l15] = (bf16_t)s[f][r];

      bf16x8 pa0 = *(const bf16x8*)&Ps[wave][l15*72 + quad*8];
      bf16x8 pa1 = *(const bf16x8*)&Ps[wave][l15*72 + 32 + quad*8];
      #pragma unroll
      for(int dn=0;dn<4;dn++){
        int row = dn*16 + l15;
        bf16x8 b0 = *(const bf16x8*)&Vs[row*64 + ((quad  ) ^ (row&7))*8];
        bf16x8 b1 = *(const bf16x8*)&Vs[row*64 + ((quad+4) ^ (row&7))*8];
        o[qf][dn] = __builtin_amdgcn_mfma_f32_16x16x32_bf16(pa0, b0, o[qf][dn], 0,0,0);
        o[qf][dn] = __builtin_amdgcn_mfma_f32_16x16x32_bf16(pa1, b1, o[qf][dn], 0,0,0);
      }
    }
    __syncthreads();
  }

  #pragma unroll
  for(int qf=0;qf<2;qf++)
    #pragma unroll
    for(int r=0;r<4;r++){
      float inv = 1.f / l_r[qf][r];
      int grow = qt*128 + wave*32 + qf*16 + quad*4 + r;
      #pragma unroll
      for(int dn=0;dn<4;dn++)
        attnO[((size_t)(b*NN + grow))*DIM + h*HD + dn*16 + l15] = (bf16_t)(o[qf][dn][r]*inv);
    }
}

// ==== proj GEMM (512 tiles, 128x64) + entropy reduction in extra block 512 ====
__global__ __launch_bounds__(256) void gemm_proj_ent(const bf16_t* __restrict__ A,
                                                     const bf16_t* __restrict__ Bt,
                                                     float* __restrict__ C,
                                                     const float* __restrict__ bias,
                                                     const float* __restrict__ entPart,
                                                     float* __restrict__ outz){
  const int bid = blockIdx.x, tid = threadIdx.x;
  if(bid == 512){                      // entropy mean (256 partials)
    float s = (tid < 256) ? entPart[tid] : 0.f;
    s += __shfl_xor(s,1); s += __shfl_xor(s,2); s += __shfl_xor(s,4);
    s += __shfl_xor(s,8); s += __shfl_xor(s,16); s += __shfl_xor(s,32);
    __shared__ float ls[4];
    if((tid&63)==0) ls[tid>>6] = s;
    __syncthreads();
    if(tid==0) outz[0] = (ls[0]+ls[1]+ls[2]+ls[3]) * (1.0f/(float)TOK);
    return;
  }
  const int K = DIM, N = DIM;
  __shared__ __align__(16) bf16_t As[128*32];
  __shared__ __align__(16) bf16_t Bs[64*32];
  const int m0 = (bid>>4)*128, n0 = (bid&15)*64;
  const int wave = tid>>6, lane = tid&63, l15 = lane&15, quad = lane>>4;
  const int wm = (wave>>1)*64, wn = (wave&1)*32;

  f32x4 acc[4][2];
  #pragma unroll
  for(int i=0;i<4;i++)
    #pragma unroll
    for(int j=0;j<2;j++) acc[i][j] = (f32x4){0.f,0.f,0.f,0.f};

  for(int k0=0; k0<K; k0+=32){
    {
      int c = tid;
      int r = c>>2, s = c&3, xs = s ^ ((r>>1)&3);
      gload16(A  + (size_t)(m0 + r)*K + k0 + xs*8, &As[c*8]);
      gload16(Bt + (size_t)(n0 + r)*K + k0 + xs*8, &Bs[c*8]);
      c = tid + 256;
      r = c>>2; s = c&3; xs = s ^ ((r>>1)&3);
      gload16(A  + (size_t)(m0 + r)*K + k0 + xs*8, &As[c*8]);
    }
    __syncthreads();

    bf16x8 a[4], b[2];
    #pragma unroll
    for(int i=0;i<4;i++){
      int R = wm + i*16 + l15;
      a[i] = *(const bf16x8*)&As[R*32 + ((quad ^ ((R>>1)&3)))*8];
    }
    #pragma unroll
    for(int j=0;j<2;j++){
      int R = wn + j*16 + l15;
      b[j] = *(const bf16x8*)&Bs[R*32 + ((quad ^ ((R>>1)&3)))*8];
    }
    #pragma unroll
    for(int i=0;i<4;i++)
      #pragma unroll
      for(int j=0;j<2;j++)
        acc[i][j] = __builtin_amdgcn_mfma_f32_16x16x32_bf16(a[i], b[j], acc[i][j], 0,0,0);
    __syncthreads();
  }

  #pragma unroll
  for(int i=0;i<4;i++)
    #pragma unroll
    for(int j=0;j<2;j++){
      int row = m0 + wm + i*16 + quad*4;
      int col = n0 + wn + j*16 + l15;
      float bv = bias[col];
      #pragma unroll
      for(int r=0;r<4;r++)
        C[(size_t)(row+r)*N + col] = acc[i][j][r] + bv;
    }
}

// ---------------- launch ----------------
extern "C" void kernel_launch(void* const* d_in, const int* in_sizes, int n_in,
                              void* d_out, int out_size, void* d_ws, size_t ws_size,
                              hipStream_t stream){
  const float* x      = (const float*)d_in[0];
  const float* Wqkv   = (const float*)d_in[1];
  const float* Wproj  = (const float*)d_in[2];
  const float* bproj  = (const float*)d_in[3];
  const float* Wgroup = (const float*)d_in[4];
  const float* bgroup = (const float*)d_in[5];
  const float* Wtheta = (const float*)d_in[6];
  const float* btheta = (const float*)d_in[7];
  const float* affB   = (const float*)d_in[8];
  const float* cps    = (const float*)d_in[9];
  float* out = (float*)d_out;
  char* ws = (char*)d_ws;

  bf16_t* xb       = (bf16_t*)(ws);                       //  8 MB
  bf16_t* WqkvT    = (bf16_t*)(ws + (size_t)8*1048576);   //  6 MB
  bf16_t* WprojT   = (bf16_t*)(ws + (size_t)14*1048576);  //  2 MB
  bf16_t* Qb       = (bf16_t*)(ws + (size_t)16*1048576);  //  8 MB
  bf16_t* Kb       = (bf16_t*)(ws + (size_t)24*1048576);  //  8 MB
  bf16_t* Vt       = (bf16_t*)(ws + (size_t)32*1048576);  //  8 MB
  bf16_t* zb16     = (bf16_t*)(ws + (size_t)40*1048576);  //  1 MB
  bf16_t* zBb16    = (bf16_t*)(ws + (size_t)41*1048576);  //  1 MB
  float*  thetaAll = (float*) (ws + (size_t)42*1048576);  // .25 MB
  float*  entPart  = (float*) (ws + (size_t)43*1048576);  // 1 KB
  bf16_t* attnO    = (bf16_t*)(ws + (size_t)44*1048576);  //  8 MB
  float*  sigB     = (float*) (ws + (size_t)52*1048576);  //  4 KB

  prep_kernel<<<8193, 256, 0, stream>>>(x, Wqkv, Wproj, affB, xb, WqkvT, WprojT,
                                        sigB, out + OUT_OFF_Z);
  gemm_qkvt<<<768, 256, 0, stream>>>(xb, WqkvT, Qb, Kb, Vt);
  token_kernel<<<256, 256, 0, stream>>>(Qb, Wgroup, bgroup, Wtheta, btheta, sigB,
                                        zb16, zBb16, thetaAll, entPart);
  attn_kernel<<<1536, 256, 0, stream>>>(Qb, Kb, Vt, zb16, zBb16, thetaAll,
                                        cps, out + CP_OFF, attnO);
  gemm_proj_ent<<<513, 256, 0, stream>>>(attnO, WprojT, out, bproj,
                                         entPart, out + OUT_OFF_Z);
}